// Round 9
// baseline (52673.114 us; speedup 1.0000x reference)
//
#include <hip/hip_runtime.h>

// ContinuousGRULayer round 9: round 8 (i8 weights, 2-level fixed-point h,
// gate-split 1024-thread shell) with A-gate register residency pushed to the
// VGPR budget: 20 slices in asm-opaque regs (80 VGPR) + 6 LDS + only 6
// streamed (was 8/6/18). G: 3 LDS + 13 streamed unchanged. Streamed bytes
// per eval: 508 KB -> 304 KB.

namespace {
constexpr int kB = 128, kT = 512, kF = 128, kH = 512, kFH = 640;
// uint4-unit offsets in d_ws
constexpr int QZ4 = 0, QR4 = 16384, QG4 = 32768;        // i8 recurrent, 32 slices/gate
constexpr int WXZ4 = 49152, WXR4 = 57344, WXG4 = 65536; // f16 x-part, 16 slices/gate
constexpr size_t CS_OFF = (size_t)73728 * 16;           // 3*512 f32 scales
constexpr float HSCL = 8128.0f;                         // h fixed-point scale (clip 2)
}  // namespace

typedef _Float16 h2_t __attribute__((ext_vector_type(2)));

__device__ __forceinline__ unsigned short f2h(float f) {
  return __builtin_bit_cast(unsigned short, (_Float16)f);
}
__device__ __forceinline__ unsigned pack2h(float a, float b) {
  return (unsigned)f2h(a) | ((unsigned)f2h(b) << 16);
}
__device__ __forceinline__ float dot2(unsigned w, unsigned h, float acc) {
  return __builtin_amdgcn_fdot2(__builtin_bit_cast(h2_t, w),
                                __builtin_bit_cast(h2_t, h), acc, false);
}
__device__ __forceinline__ float dot2x4(uint4 w, uint4 h, float acc) {
  acc = dot2(w.x, h.x, acc); acc = dot2(w.y, h.y, acc);
  acc = dot2(w.z, h.z, acc); acc = dot2(w.w, h.w, acc);
  return acc;
}
__device__ __forceinline__ uint4 pk8(const float* s) {
  const float4 a = *(const float4*)s;
  const float4 b = *(const float4*)(s + 4);
  uint4 o;
  o.x = pack2h(a.x, a.y); o.y = pack2h(a.z, a.w);
  o.z = pack2h(b.x, b.y); o.w = pack2h(b.z, b.w);
  return o;
}
__device__ __forceinline__ int sd4(unsigned a, unsigned b, int acc) {
  return __builtin_amdgcn_sdot4((int)a, (int)b, acc, false);
}
// one 16-weight i8 slice (uint4) against h hi/lo fixed-point arrays
__device__ __forceinline__ void dslice(const uint4 w, const unsigned* hh,
                                       const unsigned* hl, int p,
                                       int& ah, int& al) {
  ah = sd4(w.x, hh[4 * p + 0], ah); al = sd4(w.x, hl[4 * p + 0], al);
  ah = sd4(w.y, hh[4 * p + 1], ah); al = sd4(w.y, hl[4 * p + 1], al);
  ah = sd4(w.z, hh[4 * p + 2], ah); al = sd4(w.z, hl[4 * p + 2], al);
  ah = sd4(w.w, hh[4 * p + 3], ah); al = sd4(w.w, hl[4 * p + 3], al);
}

#define DECL_OPQ(v, ptr, s)                                          \
  uint4 v = (ptr)[(s) * kH];                                         \
  asm volatile("" : "+v"(v.x), "+v"(v.y), "+v"(v.z), "+v"(v.w))

// ---- pre-pack: i8 recurrent (per-row scale) + f16 x-part + scales ----
__global__ void quant_weights(const float* __restrict__ Wz,
                              const float* __restrict__ Wr,
                              const float* __restrict__ Wg,
                              void* __restrict__ ws) {
  const int bx = blockIdx.x;            // 0..1535 = gate*512 + j
  const int gate = bx >> 9, j = bx & 511;
  const float* W = (gate == 0) ? Wz : (gate == 1) ? Wr : Wg;
  const float* row = W + (size_t)j * kFH;
  const int lane = threadIdx.x;         // 0..63, owns recurrent cols 8l..8l+7
  uint4* ws4 = (uint4*)ws;

  const float* src = row + kF + lane * 8;
  float v[8]; float m = 0.f;
#pragma unroll
  for (int i = 0; i < 8; ++i) { v[i] = src[i]; m = fmaxf(m, fabsf(v[i])); }
#pragma unroll
  for (int off = 32; off; off >>= 1) m = fmaxf(m, __shfl_xor(m, off));
  const float inv = 127.f / m;
  unsigned u0 = 0, u1 = 0;
#pragma unroll
  for (int i = 0; i < 4; ++i) {
    int q = __float2int_rn(v[i] * inv); q = max(-127, min(127, q));
    u0 |= ((unsigned)(q & 255)) << (8 * i);
  }
#pragma unroll
  for (int i = 0; i < 4; ++i) {
    int q = __float2int_rn(v[4 + i] * inv); q = max(-127, min(127, q));
    u1 |= ((unsigned)(q & 255)) << (8 * i);
  }
  const int p = lane >> 1, sub = lane & 1;
  const int qbase = (gate == 0) ? QZ4 : (gate == 1) ? QR4 : QG4;
  *(uint2*)((char*)ws + ((size_t)(qbase + p * kH + j)) * 16 + sub * 8) =
      make_uint2(u0, u1);
  if (lane < 16) {
    const int xbase = (gate == 0) ? WXZ4 : (gate == 1) ? WXR4 : WXG4;
    ws4[xbase + lane * kH + j] = pk8(row + lane * 8);
  }
  if (lane == 0)
    ((float*)((char*)ws + CS_OFF))[gate * 512 + j] = m / (127.f * HSCL);
}

__global__ __launch_bounds__(1024, 4) void cgru_i8r(
    const float* __restrict__ x, const float* __restrict__ td,
    const float* __restrict__ bz, const float* __restrict__ br,
    const float* __restrict__ bg, const uint4* __restrict__ ws,
    float* __restrict__ out) {
  __shared__ uint4 WLa[2][6][kH];      // z|r slices 20..25     98,304 B
  __shared__ uint4 WLg[2][3][kH];      // g slices {0..2|16..18} 49,152 B
  __shared__ unsigned hh[kH / 4], hl[kH / 4];      // h hi/lo i8
  __shared__ unsigned rhh[kH / 4], rhl[kH / 4];    // r*h hi/lo
  __shared__ unsigned xpk[kF / 2];                 // x_t f16-packed
  __shared__ float gpart[kH];                      // half1's g partial

  const int b = blockIdx.x;
  const int tid = threadIdx.x;
  const int j = tid & (kH - 1);
  const int half = tid >> 9;

  const uint4* __restrict__ wQa = ws + (half ? QR4 : QZ4) + j;
  const uint4* __restrict__ wQg = ws + QG4 + j;
  const uint4* __restrict__ wxa = ws + (half ? WXR4 : WXZ4) + j;
  const uint4* __restrict__ wxg = ws + WXG4 + j;
  const float* cs = (const float*)((const char*)ws + CS_OFF);
  const float csa = cs[(half ? 512 : 0) + j];
  const float csg = cs[1024 + j];

  // ---- reg-resident A-gate slices 0..19 (asm-opaque; 80 VGPR) ----
  DECL_OPQ(a0, wQa, 0);  DECL_OPQ(a1, wQa, 1);  DECL_OPQ(a2, wQa, 2);
  DECL_OPQ(a3, wQa, 3);  DECL_OPQ(a4, wQa, 4);  DECL_OPQ(a5, wQa, 5);
  DECL_OPQ(a6, wQa, 6);  DECL_OPQ(a7, wQa, 7);  DECL_OPQ(a8, wQa, 8);
  DECL_OPQ(a9, wQa, 9);  DECL_OPQ(a10, wQa, 10); DECL_OPQ(a11, wQa, 11);
  DECL_OPQ(a12, wQa, 12); DECL_OPQ(a13, wQa, 13); DECL_OPQ(a14, wQa, 14);
  DECL_OPQ(a15, wQa, 15); DECL_OPQ(a16, wQa, 16); DECL_OPQ(a17, wQa, 17);
  DECL_OPQ(a18, wQa, 18); DECL_OPQ(a19, wQa, 19);
  // ---- LDS-resident slices ----
  {
    const uint4* qa = ws + (half ? QR4 : QZ4);
#pragma unroll
    for (int q = 0; q < 6; ++q) WLa[half][q][j] = qa[(20 + q) * kH + j];
#pragma unroll
    for (int q = 0; q < 3; ++q)
      WLg[half][q][j] = (ws + QG4)[((half ? 16 : 0) + q) * kH + j];
  }

  const float ba = half ? br[j] : bz[j];
  const float bgv = bg[j];
  float hb = 0.f, hs = 0.f, kacc = 0.f, zv = 0.f, dtv = 0.f;
  if (tid < kH / 4) { hh[tid] = 0; hl[tid] = 0; }   // h = 0

  for (int t = 0; t < kT; ++t) {
    if (tid < kF / 2) {   // stage x_t f16-packed
      const float2 xv =
          *(const float2*)(x + ((size_t)b * kT + t) * kF + 2 * tid);
      xpk[tid] = pack2h(xv.x, xv.y);
    }
    __syncthreads();      // xpk (+ init h, + LDS weights on t=0) visible

    // ---- x-part + bias, reused across all 8 RK4 evals ----
    const uint4* xp4 = (const uint4*)xpk;
    float ax = ba;
#pragma unroll 4
    for (int p = 0; p < 16; ++p) ax = dot2x4(wxa[p * kH], xp4[p], ax);
    float agx = half ? 0.f : bgv;
#pragma unroll 4
    for (int p = 0; p < 8; ++p)
      agx = dot2x4(wxg[(half * 8 + p) * kH], xp4[half * 8 + p], agx);
    if (half == 0) dtv = fminf(td[(size_t)b * kT + t], 1.0f) * 0.5f;

    for (int e = 0; e < 8; ++e) {   // 2 ODE steps x 4 RK4 stages
      const int s = e & 3;
      // ---- A dot (z or r): 20 reg + 6 LDS + 6 streamed slices ----
      int ah = 0, al = 0;
      dslice(a0, hh, hl, 0, ah, al);   dslice(a1, hh, hl, 1, ah, al);
      dslice(a2, hh, hl, 2, ah, al);   dslice(a3, hh, hl, 3, ah, al);
      dslice(a4, hh, hl, 4, ah, al);   dslice(a5, hh, hl, 5, ah, al);
      dslice(a6, hh, hl, 6, ah, al);   dslice(a7, hh, hl, 7, ah, al);
      dslice(a8, hh, hl, 8, ah, al);   dslice(a9, hh, hl, 9, ah, al);
      dslice(a10, hh, hl, 10, ah, al); dslice(a11, hh, hl, 11, ah, al);
      dslice(a12, hh, hl, 12, ah, al); dslice(a13, hh, hl, 13, ah, al);
      dslice(a14, hh, hl, 14, ah, al); dslice(a15, hh, hl, 15, ah, al);
      dslice(a16, hh, hl, 16, ah, al); dslice(a17, hh, hl, 17, ah, al);
      dslice(a18, hh, hl, 18, ah, al); dslice(a19, hh, hl, 19, ah, al);
#pragma unroll
      for (int q = 0; q < 6; ++q)
        dslice(WLa[half][q][j], hh, hl, 20 + q, ah, al);
#pragma unroll
      for (int p = 26; p < 32; ++p)
        dslice(wQa[p * kH], hh, hl, p, ah, al);
      const float aA = ax + csa * fmaf(128.f, (float)ah, (float)al);

      if (half == 0) {
        zv = 1.0f / (1.0f + __expf(-aA));
      } else {
        const float r = 1.0f / (1.0f + __expf(-aA));
        const int q15 = (int)((const char*)hh)[j] * 128 +
                        (int)((const char*)hl)[j];
        const float hv = (float)q15 * (1.0f / HSCL);
        int q = __float2int_rn(fminf(fmaxf(r * hv, -2.f), 2.f) * HSCL);
        const int hi = (q + 64) >> 7, lo = q - (hi << 7);
        ((char*)rhh)[j] = (char)hi; ((char*)rhl)[j] = (char)lo;
      }
      __syncthreads();   // #1: rh visible; h reads done

      // ---- G dot over rh: 3 LDS + 13 streamed (own K-half) ----
      int gh = 0, gl = 0;
      const int bs = half << 4;
#pragma unroll
      for (int q = 0; q < 3; ++q)
        dslice(WLg[half][q][j], rhh, rhl, bs + q, gh, gl);
#pragma unroll 4
      for (int p = bs + 3; p < bs + 16; ++p)
        dslice(wQg[p * kH], rhh, rhl, p, gh, gl);
      const float gp = agx + csg * fmaf(128.f, (float)gh, (float)gl);
      if (half == 1) gpart[j] = gp;
      __syncthreads();   // #2: gpart visible; rh reads done

      if (half == 0) {
        const float g = tanhf(gp + gpart[j]);
        const float kk = (1.0f - zv) * (g - hs);
        kacc = (s == 0) ? kk : kacc + ((s == 3) ? 1.0f : 2.0f) * kk;
        float nxt;
        if (s < 3) {
          nxt = fmaf((s == 2 ? 1.0f : 0.5f) * dtv, kk, hb);
        } else {
          hb = fmaf(dtv * (1.0f / 6.0f), kacc, hb);
          nxt = hb;
        }
        hs = nxt;
        int q = __float2int_rn(fminf(fmaxf(nxt, -2.f), 2.f) * HSCL);
        const int hi = (q + 64) >> 7, lo = q - (hi << 7);
        ((char*)hh)[j] = (char)hi; ((char*)hl)[j] = (char)lo;
      }
      __syncthreads();   // #3: new h visible
    }

    if (half == 0) out[((size_t)b * kT + t) * kH + j] = hb;  // coalesced
  }
}

extern "C" void kernel_launch(void* const* d_in, const int* in_sizes, int n_in,
                              void* d_out, int out_size, void* d_ws, size_t ws_size,
                              hipStream_t stream) {
  const float* x  = (const float*)d_in[0];
  const float* td = (const float*)d_in[1];
  const float* Wz = (const float*)d_in[2];
  const float* bz = (const float*)d_in[3];
  const float* Wr = (const float*)d_in[4];
  const float* br = (const float*)d_in[5];
  const float* Wg = (const float*)d_in[6];
  const float* bg = (const float*)d_in[7];
  float* out = (float*)d_out;

  quant_weights<<<3 * kH, 64, 0, stream>>>(Wz, Wr, Wg, d_ws);
  cgru_i8r<<<kB, 1024, 0, stream>>>(
      x, td, bz, br, bg, (const uint4*)d_ws, out);
}

// Round 10
// 36164.706 us; speedup vs baseline: 1.4565x; 1.4565x over previous
//
#include <hip/hip_runtime.h>

// ContinuousGRULayer round 10: r9 (20 asm-opaque reg-resident A slices) with
// the VGPR BUDGET actually granted: amdgpu_waves_per_eu(4,4) pins 4 waves/EU
// (which LDS=152KB already forces) -> RA budget 128 VGPR, no spill.
// r9's failure: RA kept 64-VGPR/8-wave target and spilled the 80 opaque regs
// to scratch (FETCH 21 GB). Structure/numerics identical to the r8 WIN:
// i8 weights (per-row scale), exact 2-level fixed-point h, gate-split
// 1024-thread shell, 3 barriers/eval.
//   A (z|r): 20 reg + 6 LDS + 6 streamed slices. G: 3 LDS + 13 streamed.
//   Streamed: 304 KB/eval/CU (was 508 in r8).

namespace {
constexpr int kB = 128, kT = 512, kF = 128, kH = 512, kFH = 640;
// uint4-unit offsets in d_ws
constexpr int QZ4 = 0, QR4 = 16384, QG4 = 32768;        // i8 recurrent, 32 slices/gate
constexpr int WXZ4 = 49152, WXR4 = 57344, WXG4 = 65536; // f16 x-part, 16 slices/gate
constexpr size_t CS_OFF = (size_t)73728 * 16;           // 3*512 f32 scales
constexpr float HSCL = 8128.0f;                         // h fixed-point scale (clip 2)
}  // namespace

typedef _Float16 h2_t __attribute__((ext_vector_type(2)));

__device__ __forceinline__ unsigned short f2h(float f) {
  return __builtin_bit_cast(unsigned short, (_Float16)f);
}
__device__ __forceinline__ unsigned pack2h(float a, float b) {
  return (unsigned)f2h(a) | ((unsigned)f2h(b) << 16);
}
__device__ __forceinline__ float dot2(unsigned w, unsigned h, float acc) {
  return __builtin_amdgcn_fdot2(__builtin_bit_cast(h2_t, w),
                                __builtin_bit_cast(h2_t, h), acc, false);
}
__device__ __forceinline__ float dot2x4(uint4 w, uint4 h, float acc) {
  acc = dot2(w.x, h.x, acc); acc = dot2(w.y, h.y, acc);
  acc = dot2(w.z, h.z, acc); acc = dot2(w.w, h.w, acc);
  return acc;
}
__device__ __forceinline__ uint4 pk8(const float* s) {
  const float4 a = *(const float4*)s;
  const float4 b = *(const float4*)(s + 4);
  uint4 o;
  o.x = pack2h(a.x, a.y); o.y = pack2h(a.z, a.w);
  o.z = pack2h(b.x, b.y); o.w = pack2h(b.z, b.w);
  return o;
}
__device__ __forceinline__ int sd4(unsigned a, unsigned b, int acc) {
  return __builtin_amdgcn_sdot4((int)a, (int)b, acc, false);
}
// one 16-weight i8 slice (uint4) against h hi/lo fixed-point arrays
__device__ __forceinline__ void dslice(const uint4 w, const unsigned* hh,
                                       const unsigned* hl, int p,
                                       int& ah, int& al) {
  ah = sd4(w.x, hh[4 * p + 0], ah); al = sd4(w.x, hl[4 * p + 0], al);
  ah = sd4(w.y, hh[4 * p + 1], ah); al = sd4(w.y, hl[4 * p + 1], al);
  ah = sd4(w.z, hh[4 * p + 2], ah); al = sd4(w.z, hl[4 * p + 2], al);
  ah = sd4(w.w, hh[4 * p + 3], ah); al = sd4(w.w, hl[4 * p + 3], al);
}

#define DECL_OPQ(v, ptr, s)                                          \
  uint4 v = (ptr)[(s) * kH];                                         \
  asm volatile("" : "+v"(v.x), "+v"(v.y), "+v"(v.z), "+v"(v.w))

// ---- pre-pack: i8 recurrent (per-row scale) + f16 x-part + scales ----
__global__ void quant_weights(const float* __restrict__ Wz,
                              const float* __restrict__ Wr,
                              const float* __restrict__ Wg,
                              void* __restrict__ ws) {
  const int bx = blockIdx.x;            // 0..1535 = gate*512 + j
  const int gate = bx >> 9, j = bx & 511;
  const float* W = (gate == 0) ? Wz : (gate == 1) ? Wr : Wg;
  const float* row = W + (size_t)j * kFH;
  const int lane = threadIdx.x;         // 0..63, owns recurrent cols 8l..8l+7
  uint4* ws4 = (uint4*)ws;

  const float* src = row + kF + lane * 8;
  float v[8]; float m = 0.f;
#pragma unroll
  for (int i = 0; i < 8; ++i) { v[i] = src[i]; m = fmaxf(m, fabsf(v[i])); }
#pragma unroll
  for (int off = 32; off; off >>= 1) m = fmaxf(m, __shfl_xor(m, off));
  const float inv = 127.f / m;
  unsigned u0 = 0, u1 = 0;
#pragma unroll
  for (int i = 0; i < 4; ++i) {
    int q = __float2int_rn(v[i] * inv); q = max(-127, min(127, q));
    u0 |= ((unsigned)(q & 255)) << (8 * i);
  }
#pragma unroll
  for (int i = 0; i < 4; ++i) {
    int q = __float2int_rn(v[4 + i] * inv); q = max(-127, min(127, q));
    u1 |= ((unsigned)(q & 255)) << (8 * i);
  }
  const int p = lane >> 1, sub = lane & 1;
  const int qbase = (gate == 0) ? QZ4 : (gate == 1) ? QR4 : QG4;
  *(uint2*)((char*)ws + ((size_t)(qbase + p * kH + j)) * 16 + sub * 8) =
      make_uint2(u0, u1);
  if (lane < 16) {
    const int xbase = (gate == 0) ? WXZ4 : (gate == 1) ? WXR4 : WXG4;
    ws4[xbase + lane * kH + j] = pk8(row + lane * 8);
  }
  if (lane == 0)
    ((float*)((char*)ws + CS_OFF))[gate * 512 + j] = m / (127.f * HSCL);
}

__global__ __launch_bounds__(1024)
__attribute__((amdgpu_waves_per_eu(4, 4)))
void cgru_i8r(
    const float* __restrict__ x, const float* __restrict__ td,
    const float* __restrict__ bz, const float* __restrict__ br,
    const float* __restrict__ bg, const uint4* __restrict__ ws,
    float* __restrict__ out) {
  __shared__ uint4 WLa[2][6][kH];      // z|r slices 20..25     98,304 B
  __shared__ uint4 WLg[2][3][kH];      // g slices {0..2|16..18} 49,152 B
  __shared__ unsigned hh[kH / 4], hl[kH / 4];      // h hi/lo i8
  __shared__ unsigned rhh[kH / 4], rhl[kH / 4];    // r*h hi/lo
  __shared__ unsigned xpk[kF / 2];                 // x_t f16-packed
  __shared__ float gpart[kH];                      // half1's g partial

  const int b = blockIdx.x;
  const int tid = threadIdx.x;
  const int j = tid & (kH - 1);
  const int half = tid >> 9;

  const uint4* __restrict__ wQa = ws + (half ? QR4 : QZ4) + j;
  const uint4* __restrict__ wQg = ws + QG4 + j;
  const uint4* __restrict__ wxa = ws + (half ? WXR4 : WXZ4) + j;
  const uint4* __restrict__ wxg = ws + WXG4 + j;
  const float* cs = (const float*)((const char*)ws + CS_OFF);
  const float csa = cs[(half ? 512 : 0) + j];
  const float csg = cs[1024 + j];

  // ---- reg-resident A-gate slices 0..19 (asm-opaque; 80 VGPR) ----
  DECL_OPQ(a0, wQa, 0);  DECL_OPQ(a1, wQa, 1);  DECL_OPQ(a2, wQa, 2);
  DECL_OPQ(a3, wQa, 3);  DECL_OPQ(a4, wQa, 4);  DECL_OPQ(a5, wQa, 5);
  DECL_OPQ(a6, wQa, 6);  DECL_OPQ(a7, wQa, 7);  DECL_OPQ(a8, wQa, 8);
  DECL_OPQ(a9, wQa, 9);  DECL_OPQ(a10, wQa, 10); DECL_OPQ(a11, wQa, 11);
  DECL_OPQ(a12, wQa, 12); DECL_OPQ(a13, wQa, 13); DECL_OPQ(a14, wQa, 14);
  DECL_OPQ(a15, wQa, 15); DECL_OPQ(a16, wQa, 16); DECL_OPQ(a17, wQa, 17);
  DECL_OPQ(a18, wQa, 18); DECL_OPQ(a19, wQa, 19);
  // ---- LDS-resident slices ----
  {
    const uint4* qa = ws + (half ? QR4 : QZ4);
#pragma unroll
    for (int q = 0; q < 6; ++q) WLa[half][q][j] = qa[(20 + q) * kH + j];
#pragma unroll
    for (int q = 0; q < 3; ++q)
      WLg[half][q][j] = (ws + QG4)[((half ? 16 : 0) + q) * kH + j];
  }

  const float ba = half ? br[j] : bz[j];
  const float bgv = bg[j];
  float hb = 0.f, hs = 0.f, kacc = 0.f, zv = 0.f, dtv = 0.f;
  if (tid < kH / 4) { hh[tid] = 0; hl[tid] = 0; }   // h = 0

  for (int t = 0; t < kT; ++t) {
    if (tid < kF / 2) {   // stage x_t f16-packed
      const float2 xv =
          *(const float2*)(x + ((size_t)b * kT + t) * kF + 2 * tid);
      xpk[tid] = pack2h(xv.x, xv.y);
    }
    __syncthreads();      // xpk (+ init h, + LDS weights on t=0) visible

    // ---- x-part + bias, reused across all 8 RK4 evals ----
    const uint4* xp4 = (const uint4*)xpk;
    float ax = ba;
#pragma unroll 4
    for (int p = 0; p < 16; ++p) ax = dot2x4(wxa[p * kH], xp4[p], ax);
    float agx = half ? 0.f : bgv;
#pragma unroll 4
    for (int p = 0; p < 8; ++p)
      agx = dot2x4(wxg[(half * 8 + p) * kH], xp4[half * 8 + p], agx);
    if (half == 0) dtv = fminf(td[(size_t)b * kT + t], 1.0f) * 0.5f;

    for (int e = 0; e < 8; ++e) {   // 2 ODE steps x 4 RK4 stages
      const int s = e & 3;
      // ---- A dot (z or r): 20 reg + 6 LDS + 6 streamed slices ----
      int ah = 0, al = 0;
      dslice(a0, hh, hl, 0, ah, al);   dslice(a1, hh, hl, 1, ah, al);
      dslice(a2, hh, hl, 2, ah, al);   dslice(a3, hh, hl, 3, ah, al);
      dslice(a4, hh, hl, 4, ah, al);   dslice(a5, hh, hl, 5, ah, al);
      dslice(a6, hh, hl, 6, ah, al);   dslice(a7, hh, hl, 7, ah, al);
      dslice(a8, hh, hl, 8, ah, al);   dslice(a9, hh, hl, 9, ah, al);
      dslice(a10, hh, hl, 10, ah, al); dslice(a11, hh, hl, 11, ah, al);
      dslice(a12, hh, hl, 12, ah, al); dslice(a13, hh, hl, 13, ah, al);
      dslice(a14, hh, hl, 14, ah, al); dslice(a15, hh, hl, 15, ah, al);
      dslice(a16, hh, hl, 16, ah, al); dslice(a17, hh, hl, 17, ah, al);
      dslice(a18, hh, hl, 18, ah, al); dslice(a19, hh, hl, 19, ah, al);
#pragma unroll
      for (int q = 0; q < 6; ++q)
        dslice(WLa[half][q][j], hh, hl, 20 + q, ah, al);
#pragma unroll 3
      for (int p = 26; p < 32; ++p)
        dslice(wQa[p * kH], hh, hl, p, ah, al);
      const float aA = ax + csa * fmaf(128.f, (float)ah, (float)al);

      if (half == 0) {
        zv = 1.0f / (1.0f + __expf(-aA));
      } else {
        const float r = 1.0f / (1.0f + __expf(-aA));
        const int q15 = (int)((const char*)hh)[j] * 128 +
                        (int)((const char*)hl)[j];
        const float hv = (float)q15 * (1.0f / HSCL);
        int q = __float2int_rn(fminf(fmaxf(r * hv, -2.f), 2.f) * HSCL);
        const int hi = (q + 64) >> 7, lo = q - (hi << 7);
        ((char*)rhh)[j] = (char)hi; ((char*)rhl)[j] = (char)lo;
      }
      __syncthreads();   // #1: rh visible; h reads done

      // ---- G dot over rh: 3 LDS + 13 streamed (own K-half) ----
      int gh = 0, gl = 0;
      const int bs = half << 4;
#pragma unroll
      for (int q = 0; q < 3; ++q)
        dslice(WLg[half][q][j], rhh, rhl, bs + q, gh, gl);
#pragma unroll 4
      for (int p = bs + 3; p < bs + 16; ++p)
        dslice(wQg[p * kH], rhh, rhl, p, gh, gl);
      const float gp = agx + csg * fmaf(128.f, (float)gh, (float)gl);
      if (half == 1) gpart[j] = gp;
      __syncthreads();   // #2: gpart visible; rh reads done

      if (half == 0) {
        const float g = tanhf(gp + gpart[j]);
        const float kk = (1.0f - zv) * (g - hs);
        kacc = (s == 0) ? kk : kacc + ((s == 3) ? 1.0f : 2.0f) * kk;
        float nxt;
        if (s < 3) {
          nxt = fmaf((s == 2 ? 1.0f : 0.5f) * dtv, kk, hb);
        } else {
          hb = fmaf(dtv * (1.0f / 6.0f), kacc, hb);
          nxt = hb;
        }
        hs = nxt;
        int q = __float2int_rn(fminf(fmaxf(nxt, -2.f), 2.f) * HSCL);
        const int hi = (q + 64) >> 7, lo = q - (hi << 7);
        ((char*)hh)[j] = (char)hi; ((char*)hl)[j] = (char)lo;
      }
      __syncthreads();   // #3: new h visible
    }

    if (half == 0) out[((size_t)b * kT + t) * kH + j] = hb;  // coalesced
  }
}

extern "C" void kernel_launch(void* const* d_in, const int* in_sizes, int n_in,
                              void* d_out, int out_size, void* d_ws, size_t ws_size,
                              hipStream_t stream) {
  const float* x  = (const float*)d_in[0];
  const float* td = (const float*)d_in[1];
  const float* Wz = (const float*)d_in[2];
  const float* bz = (const float*)d_in[3];
  const float* Wr = (const float*)d_in[4];
  const float* br = (const float*)d_in[5];
  const float* Wg = (const float*)d_in[6];
  const float* bg = (const float*)d_in[7];
  float* out = (float*)d_out;

  quant_weights<<<3 * kH, 64, 0, stream>>>(Wz, Wr, Wg, d_ws);
  cgru_i8r<<<kB, 1024, 0, stream>>>(
      x, td, bz, br, bg, (const uint4*)d_ws, out);
}

// Round 11
// 22360.614 us; speedup vs baseline: 2.3556x; 1.6173x over previous
//
#include <hip/hip_runtime.h>

// ContinuousGRULayer round 11: r8 WIN structure + single-level i8 h.
//   r8 = i8 weights (per-row scale), gate-split 1024-thread shell, residency
//   8 reg (asm-opaque) + 6 LDS + 18 streamed A-slices; 3 LDS + 13 streamed G.
//   Change: h/rh quantized to ONE i8 plane (clip +-1.27, scale 100) ->
//   dslice = 4 sdot4 (was 8), 192 sdot4/thread/eval (was 384).
//   Numerics: pre-act sigma ~0.0027 ~ bf16-h noise; harness floor is 1 bf16
//   ulp (0.0039), threshold 4 ulp -> predicted 2-3 ulp.
// Residency lesson locked in (r7/r9/r10): 16 waves => 64 usable VGPR/thread;
// more opaque regs spill to AGPR/scratch; fewer waves kill stream rate.

namespace {
constexpr int kB = 128, kT = 512, kF = 128, kH = 512, kFH = 640;
// uint4-unit offsets in d_ws
constexpr int QZ4 = 0, QR4 = 16384, QG4 = 32768;        // i8 recurrent, 32 slices/gate
constexpr int WXZ4 = 49152, WXR4 = 57344, WXG4 = 65536; // f16 x-part, 16 slices/gate
constexpr size_t CS_OFF = (size_t)73728 * 16;           // 3*512 f32 scales
constexpr float HSCL = 100.0f;                          // h scale (clip 1.27)
}  // namespace

typedef _Float16 h2_t __attribute__((ext_vector_type(2)));

__device__ __forceinline__ unsigned short f2h(float f) {
  return __builtin_bit_cast(unsigned short, (_Float16)f);
}
__device__ __forceinline__ unsigned pack2h(float a, float b) {
  return (unsigned)f2h(a) | ((unsigned)f2h(b) << 16);
}
__device__ __forceinline__ float dot2(unsigned w, unsigned h, float acc) {
  return __builtin_amdgcn_fdot2(__builtin_bit_cast(h2_t, w),
                                __builtin_bit_cast(h2_t, h), acc, false);
}
__device__ __forceinline__ float dot2x4(uint4 w, uint4 h, float acc) {
  acc = dot2(w.x, h.x, acc); acc = dot2(w.y, h.y, acc);
  acc = dot2(w.z, h.z, acc); acc = dot2(w.w, h.w, acc);
  return acc;
}
__device__ __forceinline__ uint4 pk8(const float* s) {
  const float4 a = *(const float4*)s;
  const float4 b = *(const float4*)(s + 4);
  uint4 o;
  o.x = pack2h(a.x, a.y); o.y = pack2h(a.z, a.w);
  o.z = pack2h(b.x, b.y); o.w = pack2h(b.z, b.w);
  return o;
}
__device__ __forceinline__ int sd4(unsigned a, unsigned b, int acc) {
  return __builtin_amdgcn_sdot4((int)a, (int)b, acc, false);
}
// one 16-weight i8 slice (uint4) against single-plane i8 h array
__device__ __forceinline__ void dslice(const uint4 w, const unsigned* hq,
                                       int p, int& acc) {
  acc = sd4(w.x, hq[4 * p + 0], acc);
  acc = sd4(w.y, hq[4 * p + 1], acc);
  acc = sd4(w.z, hq[4 * p + 2], acc);
  acc = sd4(w.w, hq[4 * p + 3], acc);
}

#define DECL_OPQ(v, ptr, s)                                          \
  uint4 v = (ptr)[(s) * kH];                                         \
  asm volatile("" : "+v"(v.x), "+v"(v.y), "+v"(v.z), "+v"(v.w))

// ---- pre-pack: i8 recurrent (per-row scale) + f16 x-part + scales ----
__global__ void quant_weights(const float* __restrict__ Wz,
                              const float* __restrict__ Wr,
                              const float* __restrict__ Wg,
                              void* __restrict__ ws) {
  const int bx = blockIdx.x;            // 0..1535 = gate*512 + j
  const int gate = bx >> 9, j = bx & 511;
  const float* W = (gate == 0) ? Wz : (gate == 1) ? Wr : Wg;
  const float* row = W + (size_t)j * kFH;
  const int lane = threadIdx.x;         // 0..63, owns recurrent cols 8l..8l+7
  uint4* ws4 = (uint4*)ws;

  const float* src = row + kF + lane * 8;
  float v[8]; float m = 0.f;
#pragma unroll
  for (int i = 0; i < 8; ++i) { v[i] = src[i]; m = fmaxf(m, fabsf(v[i])); }
#pragma unroll
  for (int off = 32; off; off >>= 1) m = fmaxf(m, __shfl_xor(m, off));
  const float inv = 127.f / m;
  unsigned u0 = 0, u1 = 0;
#pragma unroll
  for (int i = 0; i < 4; ++i) {
    int q = __float2int_rn(v[i] * inv); q = max(-127, min(127, q));
    u0 |= ((unsigned)(q & 255)) << (8 * i);
  }
#pragma unroll
  for (int i = 0; i < 4; ++i) {
    int q = __float2int_rn(v[4 + i] * inv); q = max(-127, min(127, q));
    u1 |= ((unsigned)(q & 255)) << (8 * i);
  }
  const int p = lane >> 1, sub = lane & 1;
  const int qbase = (gate == 0) ? QZ4 : (gate == 1) ? QR4 : QG4;
  *(uint2*)((char*)ws + ((size_t)(qbase + p * kH + j)) * 16 + sub * 8) =
      make_uint2(u0, u1);
  if (lane < 16) {
    const int xbase = (gate == 0) ? WXZ4 : (gate == 1) ? WXR4 : WXG4;
    ws4[xbase + lane * kH + j] = pk8(row + lane * 8);
  }
  if (lane == 0)
    ((float*)((char*)ws + CS_OFF))[gate * 512 + j] = m / (127.f * HSCL);
}

__global__ __launch_bounds__(1024, 4) void cgru_i8s(
    const float* __restrict__ x, const float* __restrict__ td,
    const float* __restrict__ bz, const float* __restrict__ br,
    const float* __restrict__ bg, const uint4* __restrict__ ws,
    float* __restrict__ out) {
  __shared__ uint4 WLa[2][6][kH];      // z|r slices 8..13      98,304 B
  __shared__ uint4 WLg[2][3][kH];      // g slices {0..2|16..18} 49,152 B
  __shared__ unsigned hq[kH / 4];      // h, i8 plane (512 B)
  __shared__ unsigned rq[kH / 4];      // r*h, i8 plane
  __shared__ unsigned xpk[kF / 2];     // x_t f16-packed
  __shared__ float gpart[kH];          // half1's g partial

  const int b = blockIdx.x;
  const int tid = threadIdx.x;
  const int j = tid & (kH - 1);
  const int half = tid >> 9;

  const uint4* __restrict__ wQa = ws + (half ? QR4 : QZ4) + j;
  const uint4* __restrict__ wQg = ws + QG4 + j;
  const uint4* __restrict__ wxa = ws + (half ? WXR4 : WXZ4) + j;
  const uint4* __restrict__ wxg = ws + WXG4 + j;
  const float* cs = (const float*)((const char*)ws + CS_OFF);
  const float csa = cs[(half ? 512 : 0) + j];
  const float csg = cs[1024 + j];

  // ---- reg-resident A-gate slices 0..7 (asm-opaque; fits 64-VGPR budget) ----
  DECL_OPQ(a0, wQa, 0); DECL_OPQ(a1, wQa, 1); DECL_OPQ(a2, wQa, 2);
  DECL_OPQ(a3, wQa, 3); DECL_OPQ(a4, wQa, 4); DECL_OPQ(a5, wQa, 5);
  DECL_OPQ(a6, wQa, 6); DECL_OPQ(a7, wQa, 7);
  // ---- LDS-resident slices ----
  {
    const uint4* qa = ws + (half ? QR4 : QZ4);
#pragma unroll
    for (int q = 0; q < 6; ++q) WLa[half][q][j] = qa[(8 + q) * kH + j];
#pragma unroll
    for (int q = 0; q < 3; ++q)
      WLg[half][q][j] = (ws + QG4)[((half ? 16 : 0) + q) * kH + j];
  }

  const float ba = half ? br[j] : bz[j];
  const float bgv = bg[j];
  float hb = 0.f, hs = 0.f, kacc = 0.f, zv = 0.f, dtv = 0.f;
  if (tid < kH / 4) hq[tid] = 0;       // h = 0

  for (int t = 0; t < kT; ++t) {
    if (tid < kF / 2) {   // stage x_t f16-packed
      const float2 xv =
          *(const float2*)(x + ((size_t)b * kT + t) * kF + 2 * tid);
      xpk[tid] = pack2h(xv.x, xv.y);
    }
    __syncthreads();      // xpk (+ init h, + LDS weights on t=0) visible

    // ---- x-part + bias, reused across all 8 RK4 evals ----
    const uint4* xp4 = (const uint4*)xpk;
    float ax = ba;
#pragma unroll 4
    for (int p = 0; p < 16; ++p) ax = dot2x4(wxa[p * kH], xp4[p], ax);
    float agx = half ? 0.f : bgv;
#pragma unroll 4
    for (int p = 0; p < 8; ++p)
      agx = dot2x4(wxg[(half * 8 + p) * kH], xp4[half * 8 + p], agx);
    if (half == 0) dtv = fminf(td[(size_t)b * kT + t], 1.0f) * 0.5f;

    for (int e = 0; e < 8; ++e) {   // 2 ODE steps x 4 RK4 stages
      const int s = e & 3;
      // ---- A dot (z or r): 8 reg + 6 LDS + 18 streamed slices ----
      int ah = 0;
      dslice(a0, hq, 0, ah); dslice(a1, hq, 1, ah);
      dslice(a2, hq, 2, ah); dslice(a3, hq, 3, ah);
      dslice(a4, hq, 4, ah); dslice(a5, hq, 5, ah);
      dslice(a6, hq, 6, ah); dslice(a7, hq, 7, ah);
#pragma unroll
      for (int q = 0; q < 6; ++q)
        dslice(WLa[half][q][j], hq, 8 + q, ah);
#pragma unroll 6
      for (int p = 14; p < 32; ++p)
        dslice(wQa[p * kH], hq, p, ah);
      const float aA = ax + csa * (float)ah;

      if (half == 0) {
        zv = 1.0f / (1.0f + __expf(-aA));
      } else {
        const float r = 1.0f / (1.0f + __expf(-aA));
        const float hv = (float)((const char*)hq)[j] * (1.0f / HSCL);
        int q = __float2int_rn(fminf(fmaxf(r * hv, -1.27f), 1.27f) * HSCL);
        ((char*)rq)[j] = (char)q;
      }
      __syncthreads();   // #1: rh visible; h reads done

      // ---- G dot over rh: 3 LDS + 13 streamed (own K-half) ----
      int gh = 0;
      const int bs = half << 4;
#pragma unroll
      for (int q = 0; q < 3; ++q)
        dslice(WLg[half][q][j], rq, bs + q, gh);
#pragma unroll 4
      for (int p = bs + 3; p < bs + 16; ++p)
        dslice(wQg[p * kH], rq, p, gh);
      const float gp = agx + csg * (float)gh;
      if (half == 1) gpart[j] = gp;
      __syncthreads();   // #2: gpart visible; rh reads done

      if (half == 0) {
        const float g = tanhf(gp + gpart[j]);
        const float kk = (1.0f - zv) * (g - hs);
        kacc = (s == 0) ? kk : kacc + ((s == 3) ? 1.0f : 2.0f) * kk;
        float nxt;
        if (s < 3) {
          nxt = fmaf((s == 2 ? 1.0f : 0.5f) * dtv, kk, hb);
        } else {
          hb = fmaf(dtv * (1.0f / 6.0f), kacc, hb);
          nxt = hb;
        }
        hs = nxt;
        int q = __float2int_rn(fminf(fmaxf(nxt, -1.27f), 1.27f) * HSCL);
        ((char*)hq)[j] = (char)q;
      }
      __syncthreads();   // #3: new h visible
    }

    if (half == 0) out[((size_t)b * kT + t) * kH + j] = hb;  // coalesced
  }
}

extern "C" void kernel_launch(void* const* d_in, const int* in_sizes, int n_in,
                              void* d_out, int out_size, void* d_ws, size_t ws_size,
                              hipStream_t stream) {
  const float* x  = (const float*)d_in[0];
  const float* td = (const float*)d_in[1];
  const float* Wz = (const float*)d_in[2];
  const float* bz = (const float*)d_in[3];
  const float* Wr = (const float*)d_in[4];
  const float* br = (const float*)d_in[5];
  const float* Wg = (const float*)d_in[6];
  const float* bg = (const float*)d_in[7];
  float* out = (float*)d_out;

  quant_weights<<<3 * kH, 64, 0, stream>>>(Wz, Wr, Wg, d_ws);
  cgru_i8s<<<kB, 1024, 0, stream>>>(
      x, td, bz, br, bg, (const uint4*)d_ws, out);
}

// Round 12
// 19354.897 us; speedup vs baseline: 2.7214x; 1.1553x over previous
//
#include <hip/hip_runtime.h>

// ContinuousGRULayer round 12: r11 WIN (i8 weights, single-level i8 h,
// gate-split 1024-thread shell, 3 barriers/eval) + x-part precompute.
//   The x-part (Wx.x_t + b, 3 gates) is t-parallel: computed for all (b,t)
//   by a feedforward kernel on all 256 CUs, stored f16 in d_ws (201 MB),
//   read by the scan as 2 scalars/thread/timestep. Removes 393 KB/timestep
//   of weight streaming + 96 dot2/thread/timestep + xpk staging + the
//   t-loop-top barrier. Falls back to the exact r11 in-loop path if
//   ws_size < ~203 MB (deterministic host-side branch).
// Residency frontier CLOSED (r6/r7/r9/r10): 16 waves => 64 arch VGPRs; 8
// opaque slices + ~52 working is the max. LDS at 151 KB.

namespace {
constexpr int kB = 128, kT = 512, kF = 128, kH = 512, kFH = 640;
// uint4-unit offsets in d_ws
constexpr int QZ4 = 0, QR4 = 16384, QG4 = 32768;        // i8 recurrent, 32 slices/gate
constexpr int WXZ4 = 49152, WXR4 = 57344, WXG4 = 65536; // f16 x-part, 16 slices/gate
constexpr size_t CS_OFF = (size_t)73728 * 16;           // 3*512 f32 scales
constexpr size_t AXP_OFF = 1310720;                     // f16 x-part results
constexpr size_t AXP_BYTES = (size_t)kB * kT * 3 * kH * 2;  // 201 MB
constexpr float HSCL = 100.0f;                          // h scale (clip 1.27)
}  // namespace

typedef _Float16 h2_t __attribute__((ext_vector_type(2)));

__device__ __forceinline__ unsigned short f2h(float f) {
  return __builtin_bit_cast(unsigned short, (_Float16)f);
}
__device__ __forceinline__ unsigned pack2h(float a, float b) {
  return (unsigned)f2h(a) | ((unsigned)f2h(b) << 16);
}
__device__ __forceinline__ float h2f(unsigned short u) {
  return (float)__builtin_bit_cast(_Float16, u);
}
__device__ __forceinline__ float dot2(unsigned w, unsigned h, float acc) {
  return __builtin_amdgcn_fdot2(__builtin_bit_cast(h2_t, w),
                                __builtin_bit_cast(h2_t, h), acc, false);
}
__device__ __forceinline__ float dot2x4(uint4 w, uint4 h, float acc) {
  acc = dot2(w.x, h.x, acc); acc = dot2(w.y, h.y, acc);
  acc = dot2(w.z, h.z, acc); acc = dot2(w.w, h.w, acc);
  return acc;
}
__device__ __forceinline__ uint4 pk8(const float* s) {
  const float4 a = *(const float4*)s;
  const float4 b = *(const float4*)(s + 4);
  uint4 o;
  o.x = pack2h(a.x, a.y); o.y = pack2h(a.z, a.w);
  o.z = pack2h(b.x, b.y); o.w = pack2h(b.z, b.w);
  return o;
}
__device__ __forceinline__ int sd4(unsigned a, unsigned b, int acc) {
  return __builtin_amdgcn_sdot4((int)a, (int)b, acc, false);
}
__device__ __forceinline__ void dslice(const uint4 w, const unsigned* hq,
                                       int p, int& acc) {
  acc = sd4(w.x, hq[4 * p + 0], acc);
  acc = sd4(w.y, hq[4 * p + 1], acc);
  acc = sd4(w.z, hq[4 * p + 2], acc);
  acc = sd4(w.w, hq[4 * p + 3], acc);
}

#define DECL_OPQ(v, ptr, s)                                          \
  uint4 v = (ptr)[(s) * kH];                                         \
  asm volatile("" : "+v"(v.x), "+v"(v.y), "+v"(v.z), "+v"(v.w))

// ---- pre-pack: i8 recurrent (per-row scale) + f16 x-part + scales ----
__global__ void quant_weights(const float* __restrict__ Wz,
                              const float* __restrict__ Wr,
                              const float* __restrict__ Wg,
                              void* __restrict__ ws) {
  const int bx = blockIdx.x;            // 0..1535 = gate*512 + j
  const int gate = bx >> 9, j = bx & 511;
  const float* W = (gate == 0) ? Wz : (gate == 1) ? Wr : Wg;
  const float* row = W + (size_t)j * kFH;
  const int lane = threadIdx.x;         // 0..63, owns recurrent cols 8l..8l+7
  uint4* ws4 = (uint4*)ws;

  const float* src = row + kF + lane * 8;
  float v[8]; float m = 0.f;
#pragma unroll
  for (int i = 0; i < 8; ++i) { v[i] = src[i]; m = fmaxf(m, fabsf(v[i])); }
#pragma unroll
  for (int off = 32; off; off >>= 1) m = fmaxf(m, __shfl_xor(m, off));
  const float inv = 127.f / m;
  unsigned u0 = 0, u1 = 0;
#pragma unroll
  for (int i = 0; i < 4; ++i) {
    int q = __float2int_rn(v[i] * inv); q = max(-127, min(127, q));
    u0 |= ((unsigned)(q & 255)) << (8 * i);
  }
#pragma unroll
  for (int i = 0; i < 4; ++i) {
    int q = __float2int_rn(v[4 + i] * inv); q = max(-127, min(127, q));
    u1 |= ((unsigned)(q & 255)) << (8 * i);
  }
  const int p = lane >> 1, sub = lane & 1;
  const int qbase = (gate == 0) ? QZ4 : (gate == 1) ? QR4 : QG4;
  *(uint2*)((char*)ws + ((size_t)(qbase + p * kH + j)) * 16 + sub * 8) =
      make_uint2(u0, u1);
  if (lane < 16) {
    const int xbase = (gate == 0) ? WXZ4 : (gate == 1) ? WXR4 : WXG4;
    ws4[xbase + lane * kH + j] = pk8(row + lane * 8);
  }
  if (lane == 0)
    ((float*)((char*)ws + CS_OFF))[gate * 512 + j] = m / (127.f * HSCL);
}

// ---- x-part precompute: ax[b][t][gate][j] = b_gate[j] + Wx_gate[j].x_t ----
__global__ __launch_bounds__(512) void xpart_pre(
    const float* __restrict__ x, const float* __restrict__ bz,
    const float* __restrict__ br, const float* __restrict__ bg,
    const uint4* __restrict__ ws, unsigned short* __restrict__ axp) {
  __shared__ unsigned xt[8][64];        // 8 timesteps x 128 f16
  const int bx = blockIdx.x;            // 0..8191
  const int b = bx >> 6;
  const int t0 = (bx & 63) * 8;
  const int tid = threadIdx.x;          // 0..511 = j
  {
    const int m = tid >> 6, c = tid & 63;
    const float2 xv =
        *(const float2*)(x + ((size_t)b * kT + t0 + m) * kF + 2 * c);
    xt[m][c] = pack2h(xv.x, xv.y);
  }
  __syncthreads();
#pragma unroll
  for (int gate = 0; gate < 3; ++gate) {
    const uint4* wx =
        ws + ((gate == 0) ? WXZ4 : (gate == 1) ? WXR4 : WXG4) + tid;
    const float bv = ((gate == 0) ? bz : (gate == 1) ? br : bg)[tid];
    float acc[8];
#pragma unroll
    for (int m = 0; m < 8; ++m) acc[m] = bv;
#pragma unroll
    for (int p = 0; p < 16; ++p) {
      const uint4 w = wx[p * kH];
#pragma unroll
      for (int m = 0; m < 8; ++m)
        acc[m] = dot2x4(w, ((const uint4*)xt[m])[p], acc[m]);
    }
#pragma unroll
    for (int m = 0; m < 8; ++m)
      axp[(((size_t)b * kT + t0 + m) * 3 + gate) * kH + tid] = f2h(acc[m]);
  }
}

template <int XPRE>
__global__ __launch_bounds__(1024, 4) void cgru_i8s(
    const float* __restrict__ x, const float* __restrict__ td,
    const float* __restrict__ bz, const float* __restrict__ br,
    const float* __restrict__ bg, const uint4* __restrict__ ws,
    const unsigned short* __restrict__ axp, float* __restrict__ out) {
  __shared__ uint4 WLa[2][6][kH];      // z|r slices 8..13      98,304 B
  __shared__ uint4 WLg[2][3][kH];      // g slices {0..2|16..18} 49,152 B
  __shared__ unsigned hq[kH / 4];      // h, i8 plane
  __shared__ unsigned rq[kH / 4];      // r*h, i8 plane
  __shared__ unsigned xpk[kF / 2];     // x_t f16-packed (fallback mode only)
  __shared__ float gpart[kH];          // half1's g partial

  const int b = blockIdx.x;
  const int tid = threadIdx.x;
  const int j = tid & (kH - 1);
  const int half = tid >> 9;

  const uint4* __restrict__ wQa = ws + (half ? QR4 : QZ4) + j;
  const uint4* __restrict__ wQg = ws + QG4 + j;
  const uint4* __restrict__ wxa = ws + (half ? WXR4 : WXZ4) + j;
  const uint4* __restrict__ wxg = ws + WXG4 + j;
  const float* cs = (const float*)((const char*)ws + CS_OFF);
  const float csa = cs[(half ? 512 : 0) + j];
  const float csg = cs[1024 + j];

  // ---- reg-resident A-gate slices 0..7 (asm-opaque; fits 64-VGPR budget) ----
  DECL_OPQ(a0, wQa, 0); DECL_OPQ(a1, wQa, 1); DECL_OPQ(a2, wQa, 2);
  DECL_OPQ(a3, wQa, 3); DECL_OPQ(a4, wQa, 4); DECL_OPQ(a5, wQa, 5);
  DECL_OPQ(a6, wQa, 6); DECL_OPQ(a7, wQa, 7);
  // ---- LDS-resident slices ----
  {
    const uint4* qa = ws + (half ? QR4 : QZ4);
#pragma unroll
    for (int q = 0; q < 6; ++q) WLa[half][q][j] = qa[(8 + q) * kH + j];
#pragma unroll
    for (int q = 0; q < 3; ++q)
      WLg[half][q][j] = (ws + QG4)[((half ? 16 : 0) + q) * kH + j];
  }

  const float ba = half ? br[j] : bz[j];
  const float bgv = bg[j];
  float hb = 0.f, hs = 0.f, kacc = 0.f, zv = 0.f, dtv = 0.f;
  if (tid < kH / 4) hq[tid] = 0;       // h = 0
  if constexpr (XPRE) __syncthreads(); // hq init + LDS weights visible

  for (int t = 0; t < kT; ++t) {
    float ax, agx;
    if constexpr (XPRE) {
      // precomputed x-parts: gate index for the A-part == half (0:z, 1:r)
      const size_t bt3 = ((size_t)b * kT + t) * 3;
      ax = h2f(axp[(bt3 + half) * kH + j]);
      agx = half ? 0.f : h2f(axp[(bt3 + 2) * kH + j]);
      if (half == 0) dtv = fminf(td[(size_t)b * kT + t], 1.0f) * 0.5f;
    } else {
      if (tid < kF / 2) {   // stage x_t f16-packed
        const float2 xv =
            *(const float2*)(x + ((size_t)b * kT + t) * kF + 2 * tid);
        xpk[tid] = pack2h(xv.x, xv.y);
      }
      __syncthreads();      // xpk (+ init h, + LDS weights on t=0) visible
      const uint4* xp4 = (const uint4*)xpk;
      ax = ba;
#pragma unroll 4
      for (int p = 0; p < 16; ++p) ax = dot2x4(wxa[p * kH], xp4[p], ax);
      agx = half ? 0.f : bgv;
#pragma unroll 4
      for (int p = 0; p < 8; ++p)
        agx = dot2x4(wxg[(half * 8 + p) * kH], xp4[half * 8 + p], agx);
      if (half == 0) dtv = fminf(td[(size_t)b * kT + t], 1.0f) * 0.5f;
    }

    for (int e = 0; e < 8; ++e) {   // 2 ODE steps x 4 RK4 stages
      const int s = e & 3;
      // ---- A dot (z or r): 8 reg + 6 LDS + 18 streamed slices ----
      int ah = 0;
      dslice(a0, hq, 0, ah); dslice(a1, hq, 1, ah);
      dslice(a2, hq, 2, ah); dslice(a3, hq, 3, ah);
      dslice(a4, hq, 4, ah); dslice(a5, hq, 5, ah);
      dslice(a6, hq, 6, ah); dslice(a7, hq, 7, ah);
#pragma unroll
      for (int q = 0; q < 6; ++q)
        dslice(WLa[half][q][j], hq, 8 + q, ah);
#pragma unroll 6
      for (int p = 14; p < 32; ++p)
        dslice(wQa[p * kH], hq, p, ah);
      const float aA = ax + csa * (float)ah;

      if (half == 0) {
        zv = 1.0f / (1.0f + __expf(-aA));
      } else {
        const float r = 1.0f / (1.0f + __expf(-aA));
        const float hv = (float)((const char*)hq)[j] * (1.0f / HSCL);
        int q = __float2int_rn(fminf(fmaxf(r * hv, -1.27f), 1.27f) * HSCL);
        ((char*)rq)[j] = (char)q;
      }
      __syncthreads();   // #1: rh visible; h reads done

      // ---- G dot over rh: 3 LDS + 13 streamed (own K-half) ----
      int gh = 0;
      const int bs = half << 4;
#pragma unroll
      for (int q = 0; q < 3; ++q)
        dslice(WLg[half][q][j], rq, bs + q, gh);
#pragma unroll 4
      for (int p = bs + 3; p < bs + 16; ++p)
        dslice(wQg[p * kH], rq, p, gh);
      const float gp = agx + csg * (float)gh;
      if (half == 1) gpart[j] = gp;
      __syncthreads();   // #2: gpart visible; rh reads done

      if (half == 0) {
        const float g = tanhf(gp + gpart[j]);
        const float kk = (1.0f - zv) * (g - hs);
        kacc = (s == 0) ? kk : kacc + ((s == 3) ? 1.0f : 2.0f) * kk;
        float nxt;
        if (s < 3) {
          nxt = fmaf((s == 2 ? 1.0f : 0.5f) * dtv, kk, hb);
        } else {
          hb = fmaf(dtv * (1.0f / 6.0f), kacc, hb);
          nxt = hb;
        }
        hs = nxt;
        int q = __float2int_rn(fminf(fmaxf(nxt, -1.27f), 1.27f) * HSCL);
        ((char*)hq)[j] = (char)q;
      }
      __syncthreads();   // #3: new h visible
    }

    if (half == 0) out[((size_t)b * kT + t) * kH + j] = hb;  // coalesced
  }
}

extern "C" void kernel_launch(void* const* d_in, const int* in_sizes, int n_in,
                              void* d_out, int out_size, void* d_ws, size_t ws_size,
                              hipStream_t stream) {
  const float* x  = (const float*)d_in[0];
  const float* td = (const float*)d_in[1];
  const float* Wz = (const float*)d_in[2];
  const float* bz = (const float*)d_in[3];
  const float* Wr = (const float*)d_in[4];
  const float* br = (const float*)d_in[5];
  const float* Wg = (const float*)d_in[6];
  const float* bg = (const float*)d_in[7];
  float* out = (float*)d_out;

  quant_weights<<<3 * kH, 64, 0, stream>>>(Wz, Wr, Wg, d_ws);

  unsigned short* axp = (unsigned short*)((char*)d_ws + AXP_OFF);
  if (ws_size >= AXP_OFF + AXP_BYTES) {
    xpart_pre<<<kB * (kT / 8), 512, 0, stream>>>(
        x, bz, br, bg, (const uint4*)d_ws, axp);
    cgru_i8s<1><<<kB, 1024, 0, stream>>>(
        x, td, bz, br, bg, (const uint4*)d_ws, axp, out);
  } else {
    cgru_i8s<0><<<kB, 1024, 0, stream>>>(
        x, td, bz, br, bg, (const uint4*)d_ws, axp, out);
  }
}